// Round 4
// baseline (603.048 us; speedup 1.0000x reference)
//
#include <hip/hip_runtime.h>
#include <cstdint>
#include <cstddef>

#define B_  2
#define S_  2048
#define D_  2560
#define H_  32
#define HD_ 80

typedef __attribute__((ext_vector_type(8))) short  short8;
typedef __attribute__((ext_vector_type(4))) float  floatx4;

__device__ __forceinline__ float b2f(unsigned short u) {
  union { unsigned int i; float f; } x; x.i = ((unsigned int)u) << 16; return x.f;
}
__device__ __forceinline__ unsigned short f2bf(float f) {
  union { float f; unsigned int i; } x; x.f = f;
  unsigned int u = x.i;
  return (unsigned short)((u + 0x7fffu + ((u >> 16) & 1u)) >> 16);
}

// fused fp32 -> bf16 for all three inputs (one launch)
__global__ void cvt3_kernel(const float* __restrict__ s0, unsigned short* __restrict__ d0, int n0,
                            const float* __restrict__ s1, unsigned short* __restrict__ d1, int n1,
                            const float* __restrict__ s2, unsigned short* __restrict__ d2, int n2) {
  int j = blockIdx.x * 256 + threadIdx.x;
  const float* s; unsigned short* d;
  if (j < n0) { s = s0; d = d0; }
  else {
    j -= n0;
    if (j < n1) { s = s1; d = d1; }
    else { j -= n1; if (j >= n2) return; s = s2; d = d2; }
  }
  const float4 v = ((const float4*)s)[j];
  ushort4 r;
  r.x = f2bf(v.x); r.y = f2bf(v.y); r.z = f2bf(v.z); r.w = f2bf(v.w);
  ((ushort4*)d)[j] = r;
}

#define GLOAD_LDS16(g, l)                                                      \
  __builtin_amdgcn_global_load_lds(                                            \
      (const __attribute__((address_space(1))) void*)(g),                      \
      (__attribute__((address_space(3))) void*)(l), 16, 0, 0)

// ============================================================================
// (MSUB*32) x 256 tile, BK=64, 8 waves (2M x 4N), double-buffered LDS.
// R4: SINGLE barrier per K-tile. R3 post-mortem: per-tile 5130 cy vs 2484 cy
// MFMA floor; LDS pipe (~2000-3000 cy) and MFMA pipe were ADDING because the
// 2 barriers/tile re-convoy the 8 waves (all-read then all-MFMA). Fix: stage
// ALL of tile t+1 (A+B halves) into buf[c^1] at tile-t TOP. buf[c^1]'s tile
// t-1 reads were consumed by t-1's MFMAs (lgkm enforced by data dependency)
// before the end-of-(t-1) barrier, so top-of-t staging is hazard-free and the
// mid-tile barrier disappears. Tile-end vmcnt(0) waits on loads issued a full
// tile (~2500 cy >> 900 cy HBM) earlier - effectively free; + barrier
// publishes all waves' DMA before tile t+1 reads. Waves free-run the whole
// tile: reads/staging/MFMA of different waves interleave (m114 overlap).
// MSUB: m-subtiles per wave. 8 -> 256-row tile (quads A,B,C,D; 128 KiB LDS);
//       4 -> 128-row tile (quads A,B; 96 KiB LDS) for grid-shape flexibility.
// T2 st_16x32 swizzle (bank-conflict = 0 measured) + T5 setprio retained.
// C[M,N] = A[M,K]*B[N,K]^T + bias[N]; same C mapping as the verified kernel.
// ============================================================================
template <int OUT_BF16, int MSUB>
__global__ __launch_bounds__(512)
void gemm256(const unsigned short* __restrict__ A,
             const unsigned short* __restrict__ Bw,
             const float* __restrict__ bias,
             void* __restrict__ Cv,
             const int M, const int N, const int K) {
  constexpr int ASH  = MSUB * 2048;   // A region per buf, shorts (16384 / 8192)
  constexpr int BSH  = 16384;         // B region per buf, shorts (256x64 bf16)
  constexpr int CBUF = ASH + BSH;     // buf stride, shorts
  __shared__ __align__(16) unsigned short sh[2 * CBUF];
  const int tid  = threadIdx.x;
  const int wave = tid >> 6;
  const int lane = tid & 63;
  const int wm = wave >> 2;        // 0..1: wave's m-half of the tile
  const int wn = wave & 3;         // 0..3: wave's 64-col slice of the N tile
  const int fr = lane & 15;
  const int fg = lane >> 4;
  const int row0 = (int)blockIdx.y * (MSUB * 32);
  const int col0 = (int)blockIdx.x << 8;
  const unsigned short* Ab = A  + (size_t)row0 * K;
  const unsigned short* Bb = Bw + (size_t)col0 * K;
  // staging: lane's source element inside one 16x32 subtile, pre-swizzled so
  // the linear DMA write realizes LDS[swz(o)] = G[o]  (swz: byte^32 if row>=8)
  const int srow = lane >> 2;                                  // subtile row 0..15
  const int scol = ((lane & 3) << 3) ^ ((lane & 32) ? 16 : 0); // elem col in 0..31
  // ds_read offset inside a subtile (shorts), same involution on the read side
  const int rdoff = fr * 32 + ((fg * 8) ^ ((fr & 8) ? 16 : 0));
  const int aOff = wm * (MSUB == 8 ? 8192 : 2048); // wave's first A row-subtile
  const int bOff = ASH + (wn >> 1) * 8192;         // B-half this wave reads
  const int rbB  = (wn & 1) * 4;                   // wave's first B rowblk in half
  const int NT = K >> 6;

  floatx4 acc[MSUB][4] = {};

#define STAGE_HALF(G, matOff, c, h, k0)                                        \
  do {                                                                         \
    _Pragma("unroll")                                                          \
    for (int i_ = 0; i_ < 2; ++i_) {                                           \
      const int s_ = (wave << 1) | i_;                                         \
      const int kk_ = s_ >> 3, rb_ = s_ & 7;                                   \
      GLOAD_LDS16((G) + (size_t)((h) * 128 + rb_ * 16 + srow) * K              \
                      + ((k0) + kk_ * 32 + scol),                              \
                  &sh[(c) * CBUF + (matOff) + (h) * 8192 + s_ * 512]);         \
    }                                                                          \
  } while (0)

  // prologue: tile0 into buf0
  STAGE_HALF(Ab, 0, 0, 0, 0);
  if (MSUB == 8) STAGE_HALF(Ab, 0, 0, 1, 0);
  STAGE_HALF(Bb, ASH, 0, 0, 0);
  STAGE_HALF(Bb, ASH, 0, 1, 0);
  asm volatile("s_waitcnt vmcnt(0)" ::: "memory");
  __builtin_amdgcn_s_barrier();

  for (int t = 0; t < NT; ++t) {
    const int c  = t & 1;
    const int cb = c * CBUF;
    // ---- stage ALL of tile t+1 into buf[c^1] (free since end of t-1) ----
    if (t + 1 < NT) {
      const int k1 = (t + 1) << 6;
      STAGE_HALF(Ab, 0, c ^ 1, 0, k1);
      if (MSUB == 8) STAGE_HALF(Ab, 0, c ^ 1, 1, k1);
      STAGE_HALF(Bb, ASH, c ^ 1, 0, k1);
      STAGE_HALF(Bb, ASH, c ^ 1, 1, k1);
    }
    short8 aL[4][2], aH[4][2], bF0[2][2], bF1[2][2];
    // ---- reads: bF0, aL first (MFMA-A operands), bF1 last ----
#pragma unroll
    for (int nj = 0; nj < 2; ++nj)
#pragma unroll
      for (int kk = 0; kk < 2; ++kk)
        bF0[nj][kk] = *(const short8*)&sh[cb + bOff + (kk * 8 + rbB + nj) * 512 + rdoff];
#pragma unroll
    for (int mi = 0; mi < 4; ++mi)
#pragma unroll
      for (int kk = 0; kk < 2; ++kk)
        aL[mi][kk] = *(const short8*)&sh[cb + aOff + (kk * 8 + mi) * 512 + rdoff];
#pragma unroll
    for (int nj = 0; nj < 2; ++nj)
#pragma unroll
      for (int kk = 0; kk < 2; ++kk)
        bF1[nj][kk] = *(const short8*)&sh[cb + bOff + (kk * 8 + rbB + 2 + nj) * 512 + rdoff];
    // ---- quadrant A: acc[0..3][0..1] = aL x bF0 ----
    __builtin_amdgcn_s_setprio(1);
#pragma unroll
    for (int kk = 0; kk < 2; ++kk)
#pragma unroll
      for (int mi = 0; mi < 4; ++mi)
#pragma unroll
        for (int nj = 0; nj < 2; ++nj)
          acc[mi][nj] = __builtin_amdgcn_mfma_f32_16x16x32_bf16(aL[mi][kk], bF0[nj][kk], acc[mi][nj], 0, 0, 0);
    __builtin_amdgcn_s_setprio(0);
    // ---- reads for quadrants C,D (MSUB==8) overlap MFMA-B ----
    if (MSUB == 8) {
#pragma unroll
      for (int mi = 0; mi < 4; ++mi)
#pragma unroll
        for (int kk = 0; kk < 2; ++kk)
          aH[mi][kk] = *(const short8*)&sh[cb + aOff + (kk * 8 + 4 + mi) * 512 + rdoff];
    }
    // ---- quadrant B: acc[0..3][2..3] = aL x bF1 ----
    __builtin_amdgcn_s_setprio(1);
#pragma unroll
    for (int kk = 0; kk < 2; ++kk)
#pragma unroll
      for (int mi = 0; mi < 4; ++mi)
#pragma unroll
        for (int nj = 0; nj < 2; ++nj)
          acc[mi][2 + nj] = __builtin_amdgcn_mfma_f32_16x16x32_bf16(aL[mi][kk], bF1[nj][kk], acc[mi][2 + nj], 0, 0, 0);
    if (MSUB == 8) {
      // ---- quadrant C: acc[4..7][2..3] = aH x bF1 ----
#pragma unroll
      for (int kk = 0; kk < 2; ++kk)
#pragma unroll
        for (int mi = 0; mi < 4; ++mi)
#pragma unroll
          for (int nj = 0; nj < 2; ++nj)
            acc[4 + mi][2 + nj] = __builtin_amdgcn_mfma_f32_16x16x32_bf16(aH[mi][kk], bF1[nj][kk], acc[4 + mi][2 + nj], 0, 0, 0);
      // ---- quadrant D: acc[4..7][0..1] = aH x bF0 ----
#pragma unroll
      for (int kk = 0; kk < 2; ++kk)
#pragma unroll
        for (int mi = 0; mi < 4; ++mi)
#pragma unroll
          for (int nj = 0; nj < 2; ++nj)
            acc[4 + mi][nj] = __builtin_amdgcn_mfma_f32_16x16x32_bf16(aH[mi][kk], bF0[nj][kk], acc[4 + mi][nj], 0, 0, 0);
    }
    __builtin_amdgcn_s_setprio(0);
    // ---- single sync point: own DMA (issued a full tile ago) + publish ----
    if (t + 1 < NT) {
      asm volatile("s_waitcnt vmcnt(0)" ::: "memory");
      __builtin_amdgcn_s_barrier();
    }
  }
#undef STAGE_HALF

  // epilogue: identical C mapping to the verified 128^2 kernel
  unsigned short* Cb = (unsigned short*)Cv;
  float* Cf = (float*)Cv;
#pragma unroll
  for (int nj = 0; nj < 4; ++nj) {
    const int col = col0 + wn * 64 + nj * 16 + fr;
    const float bv = bias[col];
#pragma unroll
    for (int mi = 0; mi < MSUB; ++mi) {
      const int rowb = row0 + wm * (MSUB * 16) + mi * 16 + fg * 4;
#pragma unroll
      for (int r = 0; r < 4; ++r) {
        const float v = acc[mi][nj][r] + bv;
        const size_t idx = (size_t)(rowb + r) * N + col;
        if (OUT_BF16) Cb[idx] = f2bf(v);
        else          Cf[idx] = v;
      }
    }
  }
}

// qkv[B,S,3,H,HD] bf16 -> Q,K [B,H,S,HD] bf16; rope; Q scaled by (1/sqrt(80))*log2(e).
__global__ void rope_kernel(const unsigned short* __restrict__ qkv,
                            unsigned short* __restrict__ Q,
                            unsigned short* __restrict__ K) {
  const int idx = blockIdx.x * 256 + threadIdx.x;
  if (idx >= B_ * S_ * H_) return;
  const int h = idx & (H_ - 1);
  const int s = (idx >> 5) & (S_ - 1);
  const int b = idx >> 16;
  const unsigned short* row = qkv + (size_t)(b * S_ + s) * (3 * D_);
  const size_t obase = ((size_t)(b * H_ + h) * S_ + s) * HD_;

  float cc[16], ssn[16];
#pragma unroll
  for (int i = 0; i < 16; i++) {
    const float ang = (float)s * exp2f((float)i * -0.83048202372184059f);
    ssn[i] = sinf(ang);
    cc[i]  = cosf(ang);
  }
  {
    const float QS = 0.11180339887498949f * 1.4426950408889634f;
    const uint4* src = (const uint4*)(row + h * HD_);
    float f[80], g[80];
#pragma unroll
    for (int i = 0; i < 10; i++) {
      uint4 t = src[i];
      const unsigned short* w = (const unsigned short*)&t;
#pragma unroll
      for (int j = 0; j < 8; j++) f[i * 8 + j] = b2f(w[j]);
    }
#pragma unroll
    for (int i = 0; i < 16; i++) {
      g[i]      = f[i] * cc[i] - f[i + 16] * ssn[i];
      g[i + 16] = f[i] * ssn[i] + f[i + 16] * cc[i];
    }
#pragma unroll
    for (int i = 32; i < 80; i++) g[i] = f[i];
    uint4* dst = (uint4*)(Q + obase);
#pragma unroll
    for (int i = 0; i < 10; i++) {
      uint4 t;
      unsigned short* w = (unsigned short*)&t;
#pragma unroll
      for (int j = 0; j < 8; j++) w[j] = f2bf(g[i * 8 + j] * QS);
      dst[i] = t;
    }
  }
  {
    const uint4* src = (const uint4*)(row + (H_ + h) * HD_);
    float f[32], g[32];
#pragma unroll
    for (int i = 0; i < 4; i++) {
      uint4 t = src[i];
      const unsigned short* w = (const unsigned short*)&t;
#pragma unroll
      for (int j = 0; j < 8; j++) f[i * 8 + j] = b2f(w[j]);
    }
#pragma unroll
    for (int i = 0; i < 16; i++) {
      g[i]      = f[i] * cc[i] - f[i + 16] * ssn[i];
      g[i + 16] = f[i] * ssn[i] + f[i + 16] * cc[i];
    }
    uint4* dst = (uint4*)(K + obase);
#pragma unroll
    for (int i = 0; i < 4; i++) {
      uint4 t;
      unsigned short* w = (unsigned short*)&t;
#pragma unroll
      for (int j = 0; j < 8; j++) w[j] = f2bf(g[i * 8 + j]);
      dst[i] = t;
    }
#pragma unroll
    for (int i = 4; i < 10; i++) dst[i] = src[i];
  }
}

// V slice of qkv -> tiles Vtile[bh][s-chunk64][80][64], cols XOR-swizzled by (d&7)*8.
__global__ __launch_bounds__(256)
void vtrans_kernel(const unsigned short* __restrict__ qkv, unsigned short* __restrict__ Vt) {
  __shared__ unsigned short T[64][88];
  const int tid = threadIdx.x;
  const int bh = blockIdx.y;
  const int b = bh >> 5, h = bh & 31;
  const int tile = blockIdx.x;
  const int s0 = tile * 64;
  for (int t = tid; t < 640; t += 256) {
    const int r = t / 10, c = t % 10;
    const size_t src = ((size_t)((b * S_ + s0 + r) * 3) + 2) * D_ + h * HD_ + c * 8;
    *(uint4*)&T[r][c * 8] = *(const uint4*)&qkv[src];
  }
  __syncthreads();
  unsigned short* tb = Vt + ((size_t)bh * 32 + tile) * 5120;
  for (int t = tid; t < 640; t += 256) {
    const int d = t / 8, sc = t % 8;
    uint4 o;
    unsigned short* w = (unsigned short*)&o;
#pragma unroll
    for (int j = 0; j < 8; j++) w[j] = T[sc * 8 + j][d];
    *(uint4*)&tb[d * 64 + ((sc * 8) ^ ((d & 7) * 8))] = o;
  }
}

// MFMA flash attention, S^T form: P lands with k contiguous per lane.
// block = 4 waves, 128 queries per (b,h); K-chunks of 64; fixed-max exp2 softmax.
__global__ __launch_bounds__(256, 4)
void attn_mfma(const unsigned short* __restrict__ Qg,
               const unsigned short* __restrict__ Kg,
               const unsigned short* __restrict__ Vtg,
               unsigned short* __restrict__ ctx) {
  __shared__ unsigned short Ks[64 * 80];    // [k][80] (DMA-contiguous)
  __shared__ unsigned short Vs[80 * 64];    // [d][64], XOR-swizzled cols (DMA-contiguous)
  __shared__ unsigned short Ts[4][32 * 40]; // per-wave P^T staging, half-chunk (32 k), pad 40

  const int tid  = threadIdx.x;
  const int wave = tid >> 6;
  const int lane = tid & 63;
  const int fr   = lane & 15;
  const int fg   = lane >> 4;
  const int bh   = blockIdx.y;
  const int qt   = (int)gridDim.x - 1 - (int)blockIdx.x;  // heavy tiles first
  const int qbase = (qt << 7) + wave * 32;

  const unsigned short* Qrow  = Qg  + (size_t)bh * S_ * HD_;
  const unsigned short* Krow  = Kg  + (size_t)bh * S_ * HD_;
  const unsigned short* Vtile = Vtg + (size_t)bh * 32 * 5120;

  // Q fragments (B-operand): rows q, contiguous d; 3rd step zeroed for fg>=2
  short8 qf[2][3];
  const short8 zfrag = {};
#pragma unroll
  for (int mi = 0; mi < 2; mi++) {
    const unsigned short* qp = Qrow + (size_t)(qbase + mi * 16 + fr) * HD_;
    qf[mi][0] = *(const short8*)&qp[fg * 8];
    qf[mi][1] = *(const short8*)&qp[32 + fg * 8];
    qf[mi][2] = (fg < 2) ? *(const short8*)&qp[64 + fg * 8] : zfrag;
  }

  floatx4 accOT[5][2] = {};   // O^T: lane holds O[q=mi*16+fr][d=dt*16+fg*4+r]
  float l_part[2] = {0.f, 0.f};

  const int nch = 2 * qt + 2;
  for (int c = 0; c < nch; c++) {
    const int k0 = c * 64;
    __syncthreads();  // prior chunk's Ks/Vs reads complete
    {
      const unsigned short* Kt = Krow + (size_t)k0 * HD_;
      for (int i = wave; i < 10; i += 4)
        GLOAD_LDS16(Kt + i * 512 + lane * 8, &Ks[i * 512]);
    }
    {
      const unsigned short* Vt = Vtile + (size_t)c * 5120;
      for (int i = wave; i < 10; i += 4)
        GLOAD_LDS16(Vt + i * 512 + lane * 8, &Vs[i * 512]);
    }
    __syncthreads();  // drains DMA

    // S^T = K Q^T: accST[ni][mi] lane holds P[q=mi*16+fr][k=ni*16+fg*4+r]
    floatx4 accST[4][2] = {};
#pragma unroll
    for (int ni = 0; ni < 4; ni++) {
      const unsigned short* kp = &Ks[(ni * 16 + fr) * 80];
      const short8 kf0 = *(const short8*)&kp[fg * 8];
      const short8 kf1 = *(const short8*)&kp[32 + fg * 8];
      const short8 kf2 = *(const short8*)&kp[64 + (fg & 1) * 8];  // fg>=2: qf side is zero
      accST[ni][0] = __builtin_amdgcn_mfma_f32_16x16x32_bf16(kf0, qf[0][0], accST[ni][0], 0, 0, 0);
      accST[ni][1] = __builtin_amdgcn_mfma_f32_16x16x32_bf16(kf0, qf[1][0], accST[ni][1], 0, 0, 0);
      accST[ni][0] = __builtin_amdgcn_mfma_f32_16x16x32_bf16(kf1, qf[0][1], accST[ni][0], 0, 0, 0);
      accST[ni][1] = __builtin_amdgcn_mfma_f32_16x16x32_bf16(kf1, qf[1][1], accST[ni][1], 0, 0, 0);
      accST[ni][0] = __builtin_amdgcn_mfma_f32_16x16x32_bf16(kf2, qf[0][2], accST[ni][0], 0, 0, 0);
      accST[ni][1] = __builtin_amdgcn_mfma_f32_16x16x32_bf16(kf2, qf[1][2], accST[ni][1], 0, 0, 0);
    }

    // causal mask (diagonal-crossing chunks only)
    if (k0 + 63 > qbase) {
#pragma unroll
      for (int ni = 0; ni < 4; ni++)
#pragma unroll
        for (int mi = 0; mi < 2; mi++) {
          const int qg = qbase + mi * 16 + fr;
#pragma unroll
          for (int r = 0; r < 4; r++) {
            const int kg = k0 + ni * 16 + fg * 4 + r;
            if (kg > qg) accST[ni][mi][r] = -1e30f;
          }
        }
    }

    // per 32-key half: exp2 -> packed P^T to LDS -> PV MFMA
#pragma unroll
    for (int hh = 0; hh < 2; hh++) {
#pragma unroll
      for (int nh = 0; nh < 2; nh++) {
        const int ni = hh * 2 + nh;
#pragma unroll
        for (int mi = 0; mi < 2; mi++) {
          const float p0 = __builtin_amdgcn_exp2f(accST[ni][mi][0]);
          const float p1 = __builtin_amdgcn_exp2f(accST[ni][mi][1]);
          const float p2 = __builtin_amdgcn_exp2f(accST[ni][mi][2]);
          const float p3 = __builtin_amdgcn_exp2f(accST[ni][mi][3]);
          l_part[mi] += (p0 + p1) + (p2 + p3);
          uint2 w;
          w.x = (unsigned)f2bf(p0) | ((unsigned)f2bf(p1) << 16);
          w.y = (unsigned)f2bf(p2) | ((unsigned)f2bf(p3) << 16);
          *(uint2*)&Ts[wave][(mi * 16 + fr) * 40 + nh * 16 + fg * 4] = w;
        }
      }
      // wave-local write->read; compiler inserts lgkmcnt
      const short8 pf0 = *(const short8*)&Ts[wave][fr * 40 + fg * 8];
      const short8 pf1 = *(const short8*)&Ts[wave][(16 + fr) * 40 + fg * 8];
      const int vcol = hh * 32 + fg * 8;
#pragma unroll
      for (int dt = 0; dt < 5; dt++) {
        const short8 vf = *(const short8*)&Vs[(dt * 16 + fr) * 64 + (vcol ^ ((fr & 7) * 8))];
        accOT[dt][0] = __builtin_amdgcn_mfma_f32_16x16x32_bf16(vf, pf0, accOT[dt][0], 0, 0, 0);
        accOT[dt][1] = __builtin_amdgcn_mfma_f32_16x16x32_bf16(vf, pf1, accOT[dt][1], 0, 0, 0);
      }
    }
  }

  // epilogue: l reduce across fg lanes; packed b64 ctx stores (4 consecutive d)
  const int b = bh >> 5, h2 = bh & 31;
#pragma unroll
  for (int mi = 0; mi < 2; mi++) {
    float s = l_part[mi];
    s += __shfl_xor(s, 16);
    s += __shfl_xor(s, 32);
    const float inv = 1.f / s;
    const size_t rowoff = (size_t)(b * S_ + qbase + mi * 16 + fr) * D_ + h2 * HD_;
#pragma unroll
    for (int dt = 0; dt < 5; dt++) {
      const float v0 = accOT[dt][mi][0] * inv;
      const float v1 = accOT[dt][mi][1] * inv;
      const float v2 = accOT[dt][mi][2] * inv;
      const float v3 = accOT[dt][mi][3] * inv;
      uint2 w;
      w.x = (unsigned)f2bf(v0) | ((unsigned)f2bf(v1) << 16);
      w.y = (unsigned)f2bf(v2) | ((unsigned)f2bf(v3) << 16);
      *(uint2*)&ctx[rowoff + dt * 16 + fg * 4] = w;
    }
  }
}

extern "C" void kernel_launch(void* const* d_in, const int* in_sizes, int n_in,
                              void* d_out, int out_size, void* d_ws, size_t ws_size,
                              hipStream_t stream) {
  (void)in_sizes; (void)n_in; (void)out_size; (void)ws_size;
  const float* x      = (const float*)d_in[0];
  const float* wqkv_w = (const float*)d_in[1];
  const float* wqkv_b = (const float*)d_in[2];
  const float* out_w  = (const float*)d_in[3];
  const float* out_b  = (const float*)d_in[4];
  char* ws = (char*)d_ws;

  unsigned short* Xb    = (unsigned short*)(ws + 0);          // 4096x2560 bf16
  unsigned short* Wqkvb = (unsigned short*)(ws + 20971520);   // 7680x2560 bf16 (dead after gemm1)
  unsigned short* qkv   = (unsigned short*)(ws + 60293120);   // 4096x7680 bf16
  unsigned short* Qb    = (unsigned short*)(ws + 123207680);  // [B,H,S,80] bf16
  unsigned short* Kb    = (unsigned short*)(ws + 144179200);  // [B,H,S,80] bf16
  unsigned short* Woutb = (unsigned short*)(ws + 165150720);  // 2560x2560 bf16; end 178.3 MB
  unsigned short* ctx   = Xb;                                 // Xb dead after gemm1
  unsigned short* Vtile = (unsigned short*)(ws + 34078720);   // 21.0 MB in dead Wqkvb tail

  cvt3_kernel<<<35840, 256, 0, stream>>>(x, Xb, 2621440,
                                         wqkv_w, Wqkvb, 4915200,
                                         out_w, Woutb, 1638400);
  gemm256<1, 8><<<dim3(30, 16), 512, 0, stream>>>(Xb, Wqkvb, wqkv_b, (void*)qkv, 4096, 7680, 2560);
  rope_kernel<<<512, 256, 0, stream>>>(qkv, Qb, Kb);
  vtrans_kernel<<<dim3(32, 64), 256, 0, stream>>>(qkv, Vtile);
  attn_mfma<<<dim3(16, 64), 256, 0, stream>>>(Qb, Kb, Vtile, ctx);
  gemm256<0, 4><<<dim3(10, 32), 512, 0, stream>>>(ctx, Woutb, out_b, d_out, 4096, 2560, 2560);
}

// Round 5
// 544.467 us; speedup vs baseline: 1.1076x; 1.1076x over previous
//
#include <hip/hip_runtime.h>
#include <cstdint>
#include <cstddef>

#define B_  2
#define S_  2048
#define D_  2560
#define H_  32
#define HD_ 80

typedef __attribute__((ext_vector_type(8))) short  short8;
typedef __attribute__((ext_vector_type(4))) float  floatx4;

__device__ __forceinline__ float b2f(unsigned short u) {
  union { unsigned int i; float f; } x; x.i = ((unsigned int)u) << 16; return x.f;
}
__device__ __forceinline__ unsigned short f2bf(float f) {
  union { float f; unsigned int i; } x; x.f = f;
  unsigned int u = x.i;
  return (unsigned short)((u + 0x7fffu + ((u >> 16) & 1u)) >> 16);
}

// fused fp32 -> bf16 for all three inputs (one launch)
__global__ void cvt3_kernel(const float* __restrict__ s0, unsigned short* __restrict__ d0, int n0,
                            const float* __restrict__ s1, unsigned short* __restrict__ d1, int n1,
                            const float* __restrict__ s2, unsigned short* __restrict__ d2, int n2) {
  int j = blockIdx.x * 256 + threadIdx.x;
  const float* s; unsigned short* d;
  if (j < n0) { s = s0; d = d0; }
  else {
    j -= n0;
    if (j < n1) { s = s1; d = d1; }
    else { j -= n1; if (j >= n2) return; s = s2; d = d2; }
  }
  const float4 v = ((const float4*)s)[j];
  ushort4 r;
  r.x = f2bf(v.x); r.y = f2bf(v.y); r.z = f2bf(v.z); r.w = f2bf(v.w);
  ((ushort4*)d)[j] = r;
}

#define GLOAD_LDS16(g, l)                                                      \
  __builtin_amdgcn_global_load_lds(                                            \
      (const __attribute__((address_space(1))) void*)(g),                      \
      (__attribute__((address_space(3))) void*)(l), 16, 0, 0)

// ============================================================================
// (MSUB*32) x 256 tile, BK=64, 8 waves (2M x 4N), double-buffered LDS.
// R4 post-mortem: gemm1 plateaued at 41% MfmaUtil — per-tile 5490cy vs 2484cy
// MFMA floor + ~2300cy LDS pipe; pipes ADD because all 8 waves read in
// lockstep and in-wave prefetch is register-walled (acc 128 AGPR + 124 VGPR
// = 252/256 cap at 2 waves/SIMD). Structure kept from R4 (1 barrier/tile).
// R5 adds: XCD-aware block swizzle (T1) — nwg%8==0 for all our launches;
// clusters same-row panels per XCD L2. MSUB=8 for BOTH gemms (R4's MSUB=4
// gemm2 regressed: 2 rounds of half-reuse tiles < 1 round at 62.5% fill).
// T2 st_16x32 swizzle (bank-conflict = 0 measured) + T5 setprio retained.
// C[M,N] = A[M,K]*B[N,K]^T + bias[N]; same C mapping as the verified kernel.
// ============================================================================
template <int OUT_BF16, int MSUB>
__global__ __launch_bounds__(512)
void gemm256(const unsigned short* __restrict__ A,
             const unsigned short* __restrict__ Bw,
             const float* __restrict__ bias,
             void* __restrict__ Cv,
             const int M, const int N, const int K) {
  constexpr int ASH  = MSUB * 2048;   // A region per buf, shorts
  constexpr int BSH  = 16384;         // B region per buf, shorts (256x64 bf16)
  constexpr int CBUF = ASH + BSH;     // buf stride, shorts
  __shared__ __align__(16) unsigned short sh[2 * CBUF];
  const int tid  = threadIdx.x;
  const int wave = tid >> 6;
  const int lane = tid & 63;
  const int wm = wave >> 2;        // 0..1: wave's m-half of the tile
  const int wn = wave & 3;         // 0..3: wave's 64-col slice of the N tile
  const int fr = lane & 15;
  const int fg = lane >> 4;
  // XCD swizzle (T1): dispatch id -> chunked logical id (nwg % 8 == 0)
  int fid = (int)(blockIdx.y * gridDim.x + blockIdx.x);
  const int nwg = (int)(gridDim.x * gridDim.y);
  const int cpx = nwg >> 3;
  fid = (fid & 7) * cpx + (fid >> 3);
  const int bx = fid % (int)gridDim.x;
  const int by = fid / (int)gridDim.x;
  const int row0 = by * (MSUB * 32);
  const int col0 = bx << 8;
  const unsigned short* Ab = A  + (size_t)row0 * K;
  const unsigned short* Bb = Bw + (size_t)col0 * K;
  // staging: lane's source element inside one 16x32 subtile, pre-swizzled so
  // the linear DMA write realizes LDS[swz(o)] = G[o]  (swz: byte^32 if row>=8)
  const int srow = lane >> 2;                                  // subtile row 0..15
  const int scol = ((lane & 3) << 3) ^ ((lane & 32) ? 16 : 0); // elem col in 0..31
  // ds_read offset inside a subtile (shorts), same involution on the read side
  const int rdoff = fr * 32 + ((fg * 8) ^ ((fr & 8) ? 16 : 0));
  const int aOff = wm * (MSUB == 8 ? 8192 : 2048); // wave's first A row-subtile
  const int bOff = ASH + (wn >> 1) * 8192;         // B-half this wave reads
  const int rbB  = (wn & 1) * 4;                   // wave's first B rowblk in half
  const int NT = K >> 6;

  floatx4 acc[MSUB][4] = {};

#define STAGE_HALF(G, matOff, c, h, k0)                                        \
  do {                                                                         \
    _Pragma("unroll")                                                          \
    for (int i_ = 0; i_ < 2; ++i_) {                                           \
      const int s_ = (wave << 1) | i_;                                         \
      const int kk_ = s_ >> 3, rb_ = s_ & 7;                                   \
      GLOAD_LDS16((G) + (size_t)((h) * 128 + rb_ * 16 + srow) * K              \
                      + ((k0) + kk_ * 32 + scol),                              \
                  &sh[(c) * CBUF + (matOff) + (h) * 8192 + s_ * 512]);         \
    }                                                                          \
  } while (0)

  // prologue: tile0 into buf0
  STAGE_HALF(Ab, 0, 0, 0, 0);
  if (MSUB == 8) STAGE_HALF(Ab, 0, 0, 1, 0);
  STAGE_HALF(Bb, ASH, 0, 0, 0);
  STAGE_HALF(Bb, ASH, 0, 1, 0);
  asm volatile("s_waitcnt vmcnt(0)" ::: "memory");
  __builtin_amdgcn_s_barrier();

  for (int t = 0; t < NT; ++t) {
    const int c  = t & 1;
    const int cb = c * CBUF;
    // ---- stage ALL of tile t+1 into buf[c^1] (free since end of t-1) ----
    if (t + 1 < NT) {
      const int k1 = (t + 1) << 6;
      STAGE_HALF(Ab, 0, c ^ 1, 0, k1);
      if (MSUB == 8) STAGE_HALF(Ab, 0, c ^ 1, 1, k1);
      STAGE_HALF(Bb, ASH, c ^ 1, 0, k1);
      STAGE_HALF(Bb, ASH, c ^ 1, 1, k1);
    }
    short8 aL[4][2], aH[4][2], bF0[2][2], bF1[2][2];
    // ---- reads: bF0, aL first (MFMA-A operands), bF1 last ----
#pragma unroll
    for (int nj = 0; nj < 2; ++nj)
#pragma unroll
      for (int kk = 0; kk < 2; ++kk)
        bF0[nj][kk] = *(const short8*)&sh[cb + bOff + (kk * 8 + rbB + nj) * 512 + rdoff];
#pragma unroll
    for (int mi = 0; mi < 4; ++mi)
#pragma unroll
      for (int kk = 0; kk < 2; ++kk)
        aL[mi][kk] = *(const short8*)&sh[cb + aOff + (kk * 8 + mi) * 512 + rdoff];
#pragma unroll
    for (int nj = 0; nj < 2; ++nj)
#pragma unroll
      for (int kk = 0; kk < 2; ++kk)
        bF1[nj][kk] = *(const short8*)&sh[cb + bOff + (kk * 8 + rbB + 2 + nj) * 512 + rdoff];
    // ---- quadrant A: acc[0..3][0..1] = aL x bF0 ----
    __builtin_amdgcn_s_setprio(1);
#pragma unroll
    for (int kk = 0; kk < 2; ++kk)
#pragma unroll
      for (int mi = 0; mi < 4; ++mi)
#pragma unroll
        for (int nj = 0; nj < 2; ++nj)
          acc[mi][nj] = __builtin_amdgcn_mfma_f32_16x16x32_bf16(aL[mi][kk], bF0[nj][kk], acc[mi][nj], 0, 0, 0);
    __builtin_amdgcn_s_setprio(0);
    // ---- reads for quadrants C,D (MSUB==8) overlap MFMA-B ----
    if (MSUB == 8) {
#pragma unroll
      for (int mi = 0; mi < 4; ++mi)
#pragma unroll
        for (int kk = 0; kk < 2; ++kk)
          aH[mi][kk] = *(const short8*)&sh[cb + aOff + (kk * 8 + 4 + mi) * 512 + rdoff];
    }
    // ---- quadrant B: acc[0..3][2..3] = aL x bF1 ----
    __builtin_amdgcn_s_setprio(1);
#pragma unroll
    for (int kk = 0; kk < 2; ++kk)
#pragma unroll
      for (int mi = 0; mi < 4; ++mi)
#pragma unroll
        for (int nj = 0; nj < 2; ++nj)
          acc[mi][2 + nj] = __builtin_amdgcn_mfma_f32_16x16x32_bf16(aL[mi][kk], bF1[nj][kk], acc[mi][2 + nj], 0, 0, 0);
    if (MSUB == 8) {
      // ---- quadrant C: acc[4..7][2..3] = aH x bF1 ----
#pragma unroll
      for (int kk = 0; kk < 2; ++kk)
#pragma unroll
        for (int mi = 0; mi < 4; ++mi)
#pragma unroll
          for (int nj = 0; nj < 2; ++nj)
            acc[4 + mi][2 + nj] = __builtin_amdgcn_mfma_f32_16x16x32_bf16(aH[mi][kk], bF1[nj][kk], acc[4 + mi][2 + nj], 0, 0, 0);
      // ---- quadrant D: acc[4..7][0..1] = aH x bF0 ----
#pragma unroll
      for (int kk = 0; kk < 2; ++kk)
#pragma unroll
        for (int mi = 0; mi < 4; ++mi)
#pragma unroll
          for (int nj = 0; nj < 2; ++nj)
            acc[4 + mi][nj] = __builtin_amdgcn_mfma_f32_16x16x32_bf16(aH[mi][kk], bF0[nj][kk], acc[4 + mi][nj], 0, 0, 0);
    }
    __builtin_amdgcn_s_setprio(0);
    // ---- single sync point: own DMA (issued a full tile ago) + publish ----
    if (t + 1 < NT) {
      asm volatile("s_waitcnt vmcnt(0)" ::: "memory");
      __builtin_amdgcn_s_barrier();
    }
  }
#undef STAGE_HALF

  // epilogue: identical C mapping to the verified 128^2 kernel
  unsigned short* Cb = (unsigned short*)Cv;
  float* Cf = (float*)Cv;
#pragma unroll
  for (int nj = 0; nj < 4; ++nj) {
    const int col = col0 + wn * 64 + nj * 16 + fr;
    const float bv = bias[col];
#pragma unroll
    for (int mi = 0; mi < MSUB; ++mi) {
      const int rowb = row0 + wm * (MSUB * 16) + mi * 16 + fg * 4;
#pragma unroll
      for (int r = 0; r < 4; ++r) {
        const float v = acc[mi][nj][r] + bv;
        const size_t idx = (size_t)(rowb + r) * N + col;
        if (OUT_BF16) Cb[idx] = f2bf(v);
        else          Cf[idx] = v;
      }
    }
  }
}

// qkv[B,S,3,H,HD] bf16 -> Q,K [B,H,S,HD] bf16; rope; Q scaled by (1/sqrt(80))*log2(e).
__global__ void rope_kernel(const unsigned short* __restrict__ qkv,
                            unsigned short* __restrict__ Q,
                            unsigned short* __restrict__ K) {
  const int idx = blockIdx.x * 256 + threadIdx.x;
  if (idx >= B_ * S_ * H_) return;
  const int h = idx & (H_ - 1);
  const int s = (idx >> 5) & (S_ - 1);
  const int b = idx >> 16;
  const unsigned short* row = qkv + (size_t)(b * S_ + s) * (3 * D_);
  const size_t obase = ((size_t)(b * H_ + h) * S_ + s) * HD_;

  float cc[16], ssn[16];
#pragma unroll
  for (int i = 0; i < 16; i++) {
    const float ang = (float)s * exp2f((float)i * -0.83048202372184059f);
    ssn[i] = sinf(ang);
    cc[i]  = cosf(ang);
  }
  {
    const float QS = 0.11180339887498949f * 1.4426950408889634f;
    const uint4* src = (const uint4*)(row + h * HD_);
    float f[80], g[80];
#pragma unroll
    for (int i = 0; i < 10; i++) {
      uint4 t = src[i];
      const unsigned short* w = (const unsigned short*)&t;
#pragma unroll
      for (int j = 0; j < 8; j++) f[i * 8 + j] = b2f(w[j]);
    }
#pragma unroll
    for (int i = 0; i < 16; i++) {
      g[i]      = f[i] * cc[i] - f[i + 16] * ssn[i];
      g[i + 16] = f[i] * ssn[i] + f[i + 16] * cc[i];
    }
#pragma unroll
    for (int i = 32; i < 80; i++) g[i] = f[i];
    uint4* dst = (uint4*)(Q + obase);
#pragma unroll
    for (int i = 0; i < 10; i++) {
      uint4 t;
      unsigned short* w = (unsigned short*)&t;
#pragma unroll
      for (int j = 0; j < 8; j++) w[j] = f2bf(g[i * 8 + j] * QS);
      dst[i] = t;
    }
  }
  {
    const uint4* src = (const uint4*)(row + (H_ + h) * HD_);
    float f[32], g[32];
#pragma unroll
    for (int i = 0; i < 4; i++) {
      uint4 t = src[i];
      const unsigned short* w = (const unsigned short*)&t;
#pragma unroll
      for (int j = 0; j < 8; j++) f[i * 8 + j] = b2f(w[j]);
    }
#pragma unroll
    for (int i = 0; i < 16; i++) {
      g[i]      = f[i] * cc[i] - f[i + 16] * ssn[i];
      g[i + 16] = f[i] * ssn[i] + f[i + 16] * cc[i];
    }
    uint4* dst = (uint4*)(K + obase);
#pragma unroll
    for (int i = 0; i < 4; i++) {
      uint4 t;
      unsigned short* w = (unsigned short*)&t;
#pragma unroll
      for (int j = 0; j < 8; j++) w[j] = f2bf(g[i * 8 + j]);
      dst[i] = t;
    }
#pragma unroll
    for (int i = 4; i < 10; i++) dst[i] = src[i];
  }
}

// V slice of qkv -> tiles Vtile[bh][s-chunk64][80][64], cols XOR-swizzled by (d&7)*8.
__global__ __launch_bounds__(256)
void vtrans_kernel(const unsigned short* __restrict__ qkv, unsigned short* __restrict__ Vt) {
  __shared__ unsigned short T[64][88];
  const int tid = threadIdx.x;
  const int bh = blockIdx.y;
  const int b = bh >> 5, h = bh & 31;
  const int tile = blockIdx.x;
  const int s0 = tile * 64;
  for (int t = tid; t < 640; t += 256) {
    const int r = t / 10, c = t % 10;
    const size_t src = ((size_t)((b * S_ + s0 + r) * 3) + 2) * D_ + h * HD_ + c * 8;
    *(uint4*)&T[r][c * 8] = *(const uint4*)&qkv[src];
  }
  __syncthreads();
  unsigned short* tb = Vt + ((size_t)bh * 32 + tile) * 5120;
  for (int t = tid; t < 640; t += 256) {
    const int d = t / 8, sc = t % 8;
    uint4 o;
    unsigned short* w = (unsigned short*)&o;
#pragma unroll
    for (int j = 0; j < 8; j++) w[j] = T[sc * 8 + j][d];
    *(uint4*)&tb[d * 64 + ((sc * 8) ^ ((d & 7) * 8))] = o;
  }
}

// ============================================================================
// MFMA flash attention, S^T form. R5: double-buffered K/V staging, ONE
// barrier per chunk. Old loop: sync; issue DMA; sync (drains DMA issued 0cy
// earlier -> ~600-900cy L2/HBM latency exposed per chunk). New loop:
//   iter c: vmcnt(0)  [chunk c's DMA, issued a full chunk earlier -> free]
//           s_barrier [all waves' c landed + all done reading c-1]
//           STAGE(c+1) into buf[(c+1)&1]   [= buf[(c-1)&1]: reads done ^]
//           compute chunk c from buf[c&1]
// Hazard: barrier(c) implies every wave's c-1 ds_reads retired (consumed by
// its MFMAs via data-dep lgkm before it reached the barrier). 20 DMA instrs
// per chunk, exactly 5 per wave (uniform vmcnt accounting).
// LDS 51.2 KB -> 3 blocks/CU (was 4); latency hiding moves from TLP to
// intra-block pipeline. XCD swizzle: cluster 8 bh per XCD for K/V L2 reuse;
// heavy-first qt order preserved within each XCD.
// ============================================================================
__global__ __launch_bounds__(256, 3)
void attn_mfma(const unsigned short* __restrict__ Qg,
               const unsigned short* __restrict__ Kg,
               const unsigned short* __restrict__ Vtg,
               unsigned short* __restrict__ ctx) {
  __shared__ unsigned short Ks[2][64 * 80];  // [buf][k][80] (DMA-contiguous)
  __shared__ unsigned short Vs[2][80 * 64];  // [buf][d][64], XOR-swizzled cols
  __shared__ unsigned short Ts[4][32 * 40];  // per-wave P^T staging, pad 40

  const int tid  = threadIdx.x;
  const int wave = tid >> 6;
  const int lane = tid & 63;
  const int fr   = lane & 15;
  const int fg   = lane >> 4;
  // XCD swizzle: 1024 blocks -> 8 XCDs x 128; bh = w>>4 clusters per XCD.
  int p = (int)(blockIdx.y * gridDim.x + blockIdx.x);
  p = (p & 7) * 128 + (p >> 3);
  const int bh = p >> 4;
  const int qt = 15 - (p & 15);              // heavy tiles first (per XCD)
  const int qbase = (qt << 7) + wave * 32;

  const unsigned short* Qrow  = Qg  + (size_t)bh * S_ * HD_;
  const unsigned short* Krow  = Kg  + (size_t)bh * S_ * HD_;
  const unsigned short* Vtile = Vtg + (size_t)bh * 32 * 5120;

  // Q fragments (B-operand): rows q, contiguous d; 3rd step zeroed for fg>=2
  short8 qf[2][3];
  const short8 zfrag = {};
#pragma unroll
  for (int mi = 0; mi < 2; mi++) {
    const unsigned short* qp = Qrow + (size_t)(qbase + mi * 16 + fr) * HD_;
    qf[mi][0] = *(const short8*)&qp[fg * 8];
    qf[mi][1] = *(const short8*)&qp[32 + fg * 8];
    qf[mi][2] = (fg < 2) ? *(const short8*)&qp[64 + fg * 8] : zfrag;
  }

  floatx4 accOT[5][2] = {};   // O^T: lane holds O[q=mi*16+fr][d=dt*16+fg*4+r]
  float l_part[2] = {0.f, 0.f};

  const int nch = 2 * qt + 2;

  // 20 DMA instrs per chunk, 5 per wave: j 0..9 -> K, j 10..19 -> V.
#define STAGE_CHUNK(c)                                                         \
  do {                                                                         \
    const int buf_ = (c) & 1;                                                  \
    const unsigned short* Kt_ = Krow + (size_t)(c) * 64 * HD_;                 \
    const unsigned short* Vt_ = Vtile + (size_t)(c) * 5120;                    \
    _Pragma("unroll")                                                          \
    for (int u_ = 0; u_ < 5; ++u_) {                                           \
      const int j_ = wave * 5 + u_;                                            \
      if (j_ < 10) GLOAD_LDS16(Kt_ + j_ * 512 + lane * 8, &Ks[buf_][j_ * 512]);\
      else GLOAD_LDS16(Vt_ + (j_ - 10) * 512 + lane * 8,                       \
                       &Vs[buf_][(j_ - 10) * 512]);                            \
    }                                                                          \
  } while (0)

  STAGE_CHUNK(0);

  for (int c = 0; c < nch; c++) {
    const int k0 = c * 64;
    const int buf = c & 1;
    asm volatile("s_waitcnt vmcnt(0)" ::: "memory");  // chunk c landed (issued 1 chunk ago)
    __builtin_amdgcn_s_barrier();                     // all waves: c landed, c-1 reads done
    if (c + 1 < nch) STAGE_CHUNK(c + 1);

    // S^T = K Q^T: accST[ni][mi] lane holds P[q=mi*16+fr][k=ni*16+fg*4+r]
    floatx4 accST[4][2] = {};
#pragma unroll
    for (int ni = 0; ni < 4; ni++) {
      const unsigned short* kp = &Ks[buf][(ni * 16 + fr) * 80];
      const short8 kf0 = *(const short8*)&kp[fg * 8];
      const short8 kf1 = *(const short8*)&kp[32 + fg * 8];
      const short8 kf2 = *(const short8*)&kp[64 + (fg & 1) * 8];  // fg>=2: qf side is zero
      accST[ni][0] = __builtin_amdgcn_mfma_f32_16x16x32_bf16(kf0, qf[0][0], accST[ni][0], 0, 0, 0);
      accST[ni][1] = __builtin_amdgcn_mfma_f32_16x16x32_bf16(kf0, qf[1][0], accST[ni][1], 0, 0, 0);
      accST[ni][0] = __builtin_amdgcn_mfma_f32_16x16x32_bf16(kf1, qf[0][1], accST[ni][0], 0, 0, 0);
      accST[ni][1] = __builtin_amdgcn_mfma_f32_16x16x32_bf16(kf1, qf[1][1], accST[ni][1], 0, 0, 0);
      accST[ni][0] = __builtin_amdgcn_mfma_f32_16x16x32_bf16(kf2, qf[0][2], accST[ni][0], 0, 0, 0);
      accST[ni][1] = __builtin_amdgcn_mfma_f32_16x16x32_bf16(kf2, qf[1][2], accST[ni][1], 0, 0, 0);
    }

    // causal mask (diagonal-crossing chunks only)
    if (k0 + 63 > qbase) {
#pragma unroll
      for (int ni = 0; ni < 4; ni++)
#pragma unroll
        for (int mi = 0; mi < 2; mi++) {
          const int qg = qbase + mi * 16 + fr;
#pragma unroll
          for (int r = 0; r < 4; r++) {
            const int kg = k0 + ni * 16 + fg * 4 + r;
            if (kg > qg) accST[ni][mi][r] = -1e30f;
          }
        }
    }

    // per 32-key half: exp2 -> packed P^T to LDS -> PV MFMA
#pragma unroll
    for (int hh = 0; hh < 2; hh++) {
#pragma unroll
      for (int nh = 0; nh < 2; nh++) {
        const int ni = hh * 2 + nh;
#pragma unroll
        for (int mi = 0; mi < 2; mi++) {
          const float p0 = __builtin_amdgcn_exp2f(accST[ni][mi][0]);
          const float p1 = __builtin_amdgcn_exp2f(accST[ni][mi][1]);
          const float p2 = __builtin_amdgcn_exp2f(accST[ni][mi][2]);
          const float p3 = __builtin_amdgcn_exp2f(accST[ni][mi][3]);
          l_part[mi] += (p0 + p1) + (p2 + p3);
          uint2 w;
          w.x = (unsigned)f2bf(p0) | ((unsigned)f2bf(p1) << 16);
          w.y = (unsigned)f2bf(p2) | ((unsigned)f2bf(p3) << 16);
          *(uint2*)&Ts[wave][(mi * 16 + fr) * 40 + nh * 16 + fg * 4] = w;
        }
      }
      // wave-local write->read; compiler inserts lgkmcnt
      const short8 pf0 = *(const short8*)&Ts[wave][fr * 40 + fg * 8];
      const short8 pf1 = *(const short8*)&Ts[wave][(16 + fr) * 40 + fg * 8];
      const int vcol = hh * 32 + fg * 8;
#pragma unroll
      for (int dt = 0; dt < 5; dt++) {
        const short8 vf = *(const short8*)&Vs[buf][(dt * 16 + fr) * 64 + (vcol ^ ((fr & 7) * 8))];
        accOT[dt][0] = __builtin_amdgcn_mfma_f32_16x16x32_bf16(vf, pf0, accOT[dt][0], 0, 0, 0);
        accOT[dt][1] = __builtin_amdgcn_mfma_f32_16x16x32_bf16(vf, pf1, accOT[dt][1], 0, 0, 0);
      }
    }
  }
#undef STAGE_CHUNK

  // epilogue: l reduce across fg lanes; packed b64 ctx stores (4 consecutive d)
  const int b = bh >> 5, h2 = bh & 31;
#pragma unroll
  for (int mi = 0; mi < 2; mi++) {
    float s = l_part[mi];
    s += __shfl_xor(s, 16);
    s += __shfl_xor(s, 32);
    const float inv = 1.f / s;
    const size_t rowoff = (size_t)(b * S_ + qbase + mi * 16 + fr) * D_ + h2 * HD_;
#pragma unroll
    for (int dt = 0; dt < 5; dt++) {
      const float v0 = accOT[dt][mi][0] * inv;
      const float v1 = accOT[dt][mi][1] * inv;
      const float v2 = accOT[dt][mi][2] * inv;
      const float v3 = accOT[dt][mi][3] * inv;
      uint2 w;
      w.x = (unsigned)f2bf(v0) | ((unsigned)f2bf(v1) << 16);
      w.y = (unsigned)f2bf(v2) | ((unsigned)f2bf(v3) << 16);
      *(uint2*)&ctx[rowoff + dt * 16 + fg * 4] = w;
    }
  }
}

extern "C" void kernel_launch(void* const* d_in, const int* in_sizes, int n_in,
                              void* d_out, int out_size, void* d_ws, size_t ws_size,
                              hipStream_t stream) {
  (void)in_sizes; (void)n_in; (void)out_size; (void)ws_size;
  const float* x      = (const float*)d_in[0];
  const float* wqkv_w = (const float*)d_in[1];
  const float* wqkv_b = (const float*)d_in[2];
  const float* out_w  = (const float*)d_in[3];
  const float* out_b  = (const float*)d_in[4];
  char* ws = (char*)d_ws;

  unsigned short* Xb    = (unsigned short*)(ws + 0);          // 4096x2560 bf16
  unsigned short* Wqkvb = (unsigned short*)(ws + 20971520);   // 7680x2560 bf16 (dead after gemm1)
  unsigned short* qkv   = (unsigned short*)(ws + 60293120);   // 4096x7680 bf16
  unsigned short* Qb    = (unsigned short*)(ws + 123207680);  // [B,H,S,80] bf16
  unsigned short* Kb    = (unsigned short*)(ws + 144179200);  // [B,H,S,80] bf16
  unsigned short* Woutb = (unsigned short*)(ws + 165150720);  // 2560x2560 bf16; end 178.3 MB
  unsigned short* ctx   = Xb;                                 // Xb dead after gemm1
  unsigned short* Vtile = (unsigned short*)(ws + 34078720);   // 21.0 MB in dead Wqkvb tail

  cvt3_kernel<<<35840, 256, 0, stream>>>(x, Xb, 2621440,
                                         wqkv_w, Wqkvb, 4915200,
                                         out_w, Woutb, 1638400);
  gemm256<1, 8><<<dim3(30, 16), 512, 0, stream>>>(Xb, Wqkvb, wqkv_b, (void*)qkv, 4096, 7680, 2560);
  rope_kernel<<<512, 256, 0, stream>>>(qkv, Qb, Kb);
  vtrans_kernel<<<dim3(32, 64), 256, 0, stream>>>(qkv, Vtile);
  attn_mfma<<<dim3(16, 64), 256, 0, stream>>>(Qb, Kb, Vtile, ctx);
  gemm256<0, 8><<<dim3(10, 16), 512, 0, stream>>>(ctx, Woutb, out_b, d_out, 4096, 2560, 2560);
}